// Round 1
// baseline (3087.941 us; speedup 1.0000x reference)
//
#include <hip/hip_runtime.h>

#define CC    192
#define EXT   76
#define PAD   76
#define HALO  13
#define INTR  50
#define NTH   256
#define TT    8192
#define BATCH 16
#define NTILES 164
#define NPROJ 29

__device__ __forceinline__ float gelu_exact(float v) {
    return 0.5f * v * (1.0f + erff(v * 0.7071067811865475f));
}
__device__ __forceinline__ float softplus_s(float v) {
    return fmaxf(v, 0.0f) + log1pf(expf(-fabsf(v)));
}

__global__ __launch_bounds__(NTH, 1) void convflow_kernel(
    const float* __restrict__ x, const float* __restrict__ xmask,
    const float* __restrict__ w_pre, const float* __restrict__ b_pre,
    const float* __restrict__ sep_w, const float* __restrict__ sep_b,
    const float* __restrict__ pw_w, const float* __restrict__ pw_b,
    const float* __restrict__ n1_g, const float* __restrict__ n1_b,
    const float* __restrict__ n2_g, const float* __restrict__ n2_b,
    const float* __restrict__ w_proj, const float* __restrict__ b_proj,
    float* __restrict__ out, float* __restrict__ logdet)
{
    extern __shared__ float smem[];
    float* __restrict__ sh  = smem;              // [CC][PAD] running h
    float* __restrict__ sy  = smem + CC*PAD;     // [CC][PAD] conv/LN/GELU out, later proj params
    float* __restrict__ sx0 = smem + 2*CC*PAD;   // [PAD]
    float* __restrict__ sx1 = sx0 + PAD;         // [PAD]
    float* __restrict__ smk = sx1 + PAD;         // [PAD]

    const int tid  = threadIdx.x;
    const int lane = tid & 63;
    const int wav  = tid >> 6;
    const int b    = blockIdx.x / NTILES;
    const int tile = blockIdx.x - b*NTILES;
    const int t0   = tile*INTR - HALO;

    // ---- stage 0: load inputs (zero outside sequence), zero sy ----
    for (int j = tid; j < EXT; j += NTH) {
        int t = t0 + j;
        bool ok = (t >= 0) && (t < TT);
        sx0[j] = ok ? x[b*2*TT + t]      : 0.0f;
        sx1[j] = ok ? x[b*2*TT + TT + t] : 0.0f;
        smk[j] = ok ? xmask[b*TT + t]    : 0.0f;
    }
    for (int e = tid; e < CC*PAD; e += NTH) sy[e] = 0.0f;
    __syncthreads();

    // ---- pre-projection: h[c][j] = x0[j]*w_pre[c] + b_pre[c] ----
    for (int e = tid; e < CC*EXT; e += NTH) {
        int c = e / EXT;
        int j = e - c*EXT;
        sh[c*PAD + j] = sx0[j]*w_pre[c] + b_pre[c];
    }
    __syncthreads();

    const int cA = lane, cB = lane + 64, cD = lane + 128;

    #pragma unroll
    for (int li = 0; li < 3; ++li) {
        constexpr int DILA[3] = {1, 3, 9};
        constexpr int JLOA[3] = {1, 4, 13};
        constexpr int JLOM[3] = {0, 4, 12};
        constexpr int JHIM[3] = {76, 72, 64};
        constexpr int CWA[3]  = {20, 20, 16};
        const int dil = DILA[li];
        const int jlo = JLOA[li], jhi = EXT - JLOA[li];

        // ---- depthwise dilated conv + LN1 + GELU -> sy ----
        {
            float k0a = sep_w[(li*3+0)*CC + cA], k1a = sep_w[(li*3+1)*CC + cA], k2a = sep_w[(li*3+2)*CC + cA];
            float k0b = sep_w[(li*3+0)*CC + cB], k1b = sep_w[(li*3+1)*CC + cB], k2b = sep_w[(li*3+2)*CC + cB];
            float k0d = sep_w[(li*3+0)*CC + cD], k1d = sep_w[(li*3+1)*CC + cD], k2d = sep_w[(li*3+2)*CC + cD];
            float cba = sep_b[li*CC + cA], cbb = sep_b[li*CC + cB], cbd = sep_b[li*CC + cD];
            float g1a = n1_g[li*CC + cA], g1b = n1_g[li*CC + cB], g1d = n1_g[li*CC + cD];
            float b1a = n1_b[li*CC + cA], b1b = n1_b[li*CC + cB], b1d = n1_b[li*CC + cD];
            for (int j = jlo + wav; j < jhi; j += 4) {
                float m0 = smk[j-dil], m1 = smk[j], m2 = smk[j+dil];
                float aa = k0a*sh[cA*PAD + j-dil]*m0 + k1a*sh[cA*PAD + j]*m1 + k2a*sh[cA*PAD + j+dil]*m2 + cba;
                float ab = k0b*sh[cB*PAD + j-dil]*m0 + k1b*sh[cB*PAD + j]*m1 + k2b*sh[cB*PAD + j+dil]*m2 + cbb;
                float ad = k0d*sh[cD*PAD + j-dil]*m0 + k1d*sh[cD*PAD + j]*m1 + k2d*sh[cD*PAD + j+dil]*m2 + cbd;
                float s = aa+ab+ad, ss = aa*aa+ab*ab+ad*ad;
                #pragma unroll
                for (int mm = 1; mm < 64; mm <<= 1) { s += __shfl_xor(s, mm, 64); ss += __shfl_xor(ss, mm, 64); }
                float mean = s*(1.0f/CC);
                float var  = ss*(1.0f/CC) - mean*mean;
                float rstd = rsqrtf(var + 1e-5f);
                sy[cA*PAD + j] = gelu_exact((aa-mean)*rstd*g1a + b1a);
                sy[cB*PAD + j] = gelu_exact((ab-mean)*rstd*g1b + b1b);
                sy[cD*PAD + j] = gelu_exact((ad-mean)*rstd*g1d + b1d);
            }
        }
        __syncthreads();

        // ---- pointwise 192x192 + LN2 + GELU + residual into sh ----
        {
            const int cw_ = CWA[li];
            const int js  = JLOM[li] + wav*cw_;
            const int je  = min(js + cw_, JHIM[li]);
            const int cnt = je - js;       // always >0, multiple of 4
            const int nq4 = cnt >> 2;
            const float* W   = pw_w + li*CC*CC;
            const float* Wr0 = W + cA*CC;
            const float* Wr1 = W + cB*CC;
            const float* Wr2 = W + cD*CC;
            float pb0 = pw_b[li*CC + cA], pb1 = pw_b[li*CC + cB], pb2 = pw_b[li*CC + cD];
            float acc0[20], acc1[20], acc2[20];
            #pragma unroll
            for (int q = 0; q < 20; ++q) { acc0[q]=pb0; acc1[q]=pb1; acc2[q]=pb2; }
            for (int c4 = 0; c4 < CC; c4 += 4) {
                float4 w0v = *(const float4*)(Wr0 + c4);
                float4 w1v = *(const float4*)(Wr1 + c4);
                float4 w2v = *(const float4*)(Wr2 + c4);
                #pragma unroll
                for (int ccq = 0; ccq < 4; ++ccq) {
                    const float wa = (ccq==0)?w0v.x:(ccq==1)?w0v.y:(ccq==2)?w0v.z:w0v.w;
                    const float wb = (ccq==0)?w1v.x:(ccq==1)?w1v.y:(ccq==2)?w1v.z:w1v.w;
                    const float wc = (ccq==0)?w2v.x:(ccq==1)?w2v.y:(ccq==2)?w2v.z:w2v.w;
                    const float* yp = sy + (c4+ccq)*PAD + js;
                    #pragma unroll
                    for (int q4 = 0; q4 < 5; ++q4) {
                        if (q4 < nq4) {
                            float4 yv = *(const float4*)(yp + 4*q4);
                            acc0[4*q4+0] += wa*yv.x; acc0[4*q4+1] += wa*yv.y;
                            acc0[4*q4+2] += wa*yv.z; acc0[4*q4+3] += wa*yv.w;
                            acc1[4*q4+0] += wb*yv.x; acc1[4*q4+1] += wb*yv.y;
                            acc1[4*q4+2] += wb*yv.z; acc1[4*q4+3] += wb*yv.w;
                            acc2[4*q4+0] += wc*yv.x; acc2[4*q4+1] += wc*yv.y;
                            acc2[4*q4+2] += wc*yv.z; acc2[4*q4+3] += wc*yv.w;
                        }
                    }
                }
            }
            float g20 = n2_g[li*CC + cA], g21 = n2_g[li*CC + cB], g22 = n2_g[li*CC + cD];
            float b20 = n2_b[li*CC + cA], b21 = n2_b[li*CC + cB], b22 = n2_b[li*CC + cD];
            #pragma unroll
            for (int q = 0; q < 20; ++q) {
                if (q < cnt) {
                    int j = js + q;
                    float z0 = acc0[q], z1 = acc1[q], z2 = acc2[q];
                    float s = z0+z1+z2, ss = z0*z0+z1*z1+z2*z2;
                    #pragma unroll
                    for (int mm = 1; mm < 64; mm <<= 1) { s += __shfl_xor(s, mm, 64); ss += __shfl_xor(ss, mm, 64); }
                    float mean = s*(1.0f/CC);
                    float var  = ss*(1.0f/CC) - mean*mean;
                    float rstd = rsqrtf(var + 1e-5f);
                    sh[cA*PAD + j] += gelu_exact((z0-mean)*rstd*g20 + b20);
                    sh[cB*PAD + j] += gelu_exact((z1-mean)*rstd*g21 + b21);
                    sh[cD*PAD + j] += gelu_exact((z2-mean)*rstd*g22 + b22);
                }
            }
        }
        __syncthreads();
    }

    // ---- final projection: 29 spline params per column into sy rows 0..28 ----
    for (int j = HALO + wav; j < HALO + INTR; j += 4) {
        if (lane < NPROJ) {
            const float* Wp = w_proj + lane*CC;
            float sum = 0.0f;
            for (int c4 = 0; c4 < CC; c4 += 4) {
                float4 wv = *(const float4*)(Wp + c4);
                sum += wv.x*sh[(c4+0)*PAD + j];
                sum += wv.y*sh[(c4+1)*PAD + j];
                sum += wv.z*sh[(c4+2)*PAD + j];
                sum += wv.w*sh[(c4+3)*PAD + j];
            }
            float mj = smk[j];
            sy[lane*PAD + j] = (sum*mj + b_proj[lane])*mj;
        }
    }
    __syncthreads();

    // ---- rational-quadratic spline + outputs (wave 0 only) ----
    if (tid < 64) {
        int j = HALO + tid;
        int t = t0 + j;             // >= 0 always for interior
        float ladm = 0.0f;
        if (tid < INTR && t < TT) {
            const float SCALE = 0.07216878364870323f;  // 1/sqrt(192)
            float mj = smk[j];
            float uw[10], uh[10];
            #pragma unroll
            for (int k = 0; k < 10; ++k) {
                uw[k] = sy[k*PAD + j] * SCALE;
                uh[k] = sy[(10+k)*PAD + j] * SCALE;
            }
            // widths softmax -> cumwidths
            float mxw = uw[0];
            #pragma unroll
            for (int k = 1; k < 10; ++k) mxw = fmaxf(mxw, uw[k]);
            float ew[10]; float sew = 0.0f;
            #pragma unroll
            for (int k = 0; k < 10; ++k) { ew[k] = expf(uw[k]-mxw); sew += ew[k]; }
            float invw = 1.0f/sew;
            float cw[11]; cw[0] = -5.0f;
            float run = 0.0f;
            #pragma unroll
            for (int k = 0; k < 10; ++k) { run += 0.001f + 0.99f*ew[k]*invw; cw[k+1] = -5.0f + 10.0f*run; }
            cw[10] = 5.0f;
            // heights softmax -> cumheights
            float mxh = uh[0];
            #pragma unroll
            for (int k = 1; k < 10; ++k) mxh = fmaxf(mxh, uh[k]);
            float eh[10]; float seh = 0.0f;
            #pragma unroll
            for (int k = 0; k < 10; ++k) { eh[k] = expf(uh[k]-mxh); seh += eh[k]; }
            float invh = 1.0f/seh;
            float ch[11]; ch[0] = -5.0f;
            run = 0.0f;
            #pragma unroll
            for (int k = 0; k < 10; ++k) { run += 0.001f + 0.99f*eh[k]*invh; ch[k+1] = -5.0f + 10.0f*run; }
            ch[10] = 5.0f;
            // derivatives
            float dd[11];
            dd[0] = 0.001f + softplus_s(0.5397424698f);   // pad const = log(exp(0.999)-1)
            #pragma unroll
            for (int k = 0; k < 9; ++k) dd[k+1] = 0.001f + softplus_s(sy[(20+k)*PAD + j]);
            dd[10] = dd[0];

            float xv = sx1[j];
            bool inside = (xv >= -5.0f) && (xv <= 5.0f);
            float xi = fminf(fmaxf(xv, -5.0f), 5.0f);
            int idx = 0;
            #pragma unroll
            for (int k = 1; k <= 9; ++k) idx = (xi >= cw[k]) ? k : idx;
            float in_cw=0, in_w=1, in_ch=0, in_h=1, in_d=1, d_p=1;
            #pragma unroll
            for (int k = 0; k < 10; ++k) {
                if (k == idx) {
                    in_cw = cw[k]; in_w = cw[k+1]-cw[k];
                    in_ch = ch[k]; in_h = ch[k+1]-ch[k];
                    in_d  = dd[k]; d_p  = dd[k+1];
                }
            }
            float delta = in_h/in_w;
            float th  = (xi - in_cw)/in_w;
            float th1 = th*(1.0f-th);
            float num = in_h*(delta*th*th + in_d*th1);
            float den = delta + (in_d + d_p - 2.0f*delta)*th1;
            float yv  = in_ch + num/den;
            float omt = 1.0f - th;
            float dnum = delta*delta*(d_p*th*th + 2.0f*delta*th1 + in_d*omt*omt);
            float lad = logf(dnum) - 2.0f*logf(den);
            if (!inside) { yv = xv; lad = 0.0f; }
            out[b*2*TT + t]      = sx0[j]*mj;
            out[b*2*TT + TT + t] = yv*mj;
            ladm = lad*mj;
        }
        #pragma unroll
        for (int mm = 1; mm < 64; mm <<= 1) ladm += __shfl_xor(ladm, mm, 64);
        if (tid == 0) atomicAdd(&logdet[b], ladm);
    }
}

extern "C" void kernel_launch(void* const* d_in, const int* in_sizes, int n_in,
                              void* d_out, int out_size, void* d_ws, size_t ws_size,
                              hipStream_t stream) {
    const float* x      = (const float*)d_in[0];
    const float* xmask  = (const float*)d_in[1];
    const float* w_pre  = (const float*)d_in[2];
    const float* b_pre  = (const float*)d_in[3];
    const float* sep_w  = (const float*)d_in[4];
    const float* sep_b  = (const float*)d_in[5];
    const float* pw_w   = (const float*)d_in[6];
    const float* pw_b   = (const float*)d_in[7];
    const float* n1_g   = (const float*)d_in[8];
    const float* n1_b   = (const float*)d_in[9];
    const float* n2_g   = (const float*)d_in[10];
    const float* n2_b   = (const float*)d_in[11];
    const float* w_proj = (const float*)d_in[12];
    const float* b_proj = (const float*)d_in[13];
    float* out = (float*)d_out;
    float* logdet = out + (size_t)BATCH*2*TT;   // 262144

    hipMemsetAsync((void*)logdet, 0, BATCH*sizeof(float), stream);

    size_t shbytes = (size_t)(2*CC*PAD + 3*PAD) * sizeof(float);  // ~115 KiB
    dim3 grid(BATCH*NTILES);
    convflow_kernel<<<grid, NTH, shbytes, stream>>>(
        x, xmask, w_pre, b_pre, sep_w, sep_b, pw_w, pw_b,
        n1_g, n1_b, n2_g, n2_b, w_proj, b_proj, out, logdet);
}

// Round 2
// 1263.441 us; speedup vs baseline: 2.4441x; 2.4441x over previous
//
#include <hip/hip_runtime.h>

#define CC    192
#define EXT   76
#define PADH  77          // sh stride: 77 mod 32 = 13 (odd) -> conflict-free
#define LDK   200         // syt (bf16) stride: 400B rows, uniform bank quads
#define NTH   320         // 5 waves = 5 N-tiles of 16 cols
#define NW    5
#define HALO  13
#define INTR  50
#define TT    8192
#define BATCH 16
#define NTILES 164
#define NPROJ 29

typedef __bf16 bf16x8 __attribute__((ext_vector_type(8)));
typedef float  f32x4  __attribute__((ext_vector_type(4)));

__device__ __forceinline__ float gelu_exact(float v) {
    return 0.5f * v * (1.0f + erff(v * 0.7071067811865475f));
}
__device__ __forceinline__ float softplus_s(float v) {
    return fmaxf(v, 0.0f) + log1pf(expf(-fabsf(v)));
}

// Prepack pw_w (3x192x192 fp32) into MFMA A-fragment-ordered bf16:
// wq[(((li*6+ks)*12+mt)*64 + lane)*8 + e] = W[li][16mt+(lane&15)][32ks+8*(lane>>4)+e]
__global__ __launch_bounds__(256) void prepack_kernel(const float* __restrict__ pw_w,
                                                      __bf16* __restrict__ wq) {
    int idx = blockIdx.x * 256 + threadIdx.x;
    if (idx >= 3 * 6 * 12 * 512) return;
    int e    = idx & 7;
    int lane = (idx >> 3) & 63;
    int r    = idx >> 9;
    int mt   = r % 12;
    int ks   = (r / 12) % 6;
    int li   = r / 72;
    int o = 16 * mt + (lane & 15);
    int c = 32 * ks + 8 * (lane >> 4) + e;
    wq[idx] = (__bf16)pw_w[((size_t)li * CC + o) * CC + c];
}

__global__ __launch_bounds__(NTH, 1) void convflow_kernel(
    const float* __restrict__ x, const float* __restrict__ xmask,
    const float* __restrict__ w_pre, const float* __restrict__ b_pre,
    const float* __restrict__ sep_w, const float* __restrict__ sep_b,
    const __bf16* __restrict__ wq, const float* __restrict__ pw_b,
    const float* __restrict__ n1_g, const float* __restrict__ n1_b,
    const float* __restrict__ n2_g, const float* __restrict__ n2_b,
    const float* __restrict__ w_proj, const float* __restrict__ b_proj,
    float* __restrict__ out, float* __restrict__ logdet)
{
    extern __shared__ float smem[];
    float*  __restrict__ sh   = smem;                       // [192][77] fp32
    __bf16* __restrict__ syt  = (__bf16*)(smem + CC*PADH);  // [80][200] bf16 (transposed y)
    float*  __restrict__ sytf = smem + CC*PADH;             // alias: zero-init + sproj
    float*  __restrict__ spb  = smem + CC*PADH + 8000;      // [192]
    float*  __restrict__ sg2  = spb + CC;                   // [192]
    float*  __restrict__ sb2  = sg2 + CC;                   // [192]
    float*  __restrict__ sx0  = sb2 + CC;                   // [80]
    float*  __restrict__ sx1  = sx0 + 80;
    float*  __restrict__ smk  = sx1 + 80;

    const int tid  = threadIdx.x;
    const int lane = tid & 63;
    const int wav  = tid >> 6;      // 0..4
    const int b    = blockIdx.x / NTILES;
    const int tile = blockIdx.x - b * NTILES;
    const int t0   = tile * INTR - HALO;

    // ---- stage 0: inputs + zero syt ----
    for (int j = tid; j < 80; j += NTH) {
        int t = t0 + j;
        bool ok = (j < EXT) && (t >= 0) && (t < TT);
        sx0[j] = ok ? x[b*2*TT + t]      : 0.0f;
        sx1[j] = ok ? x[b*2*TT + TT + t] : 0.0f;
        smk[j] = ok ? xmask[b*TT + t]    : 0.0f;
    }
    for (int e = tid; e < 8000; e += NTH) sytf[e] = 0.0f;
    __syncthreads();

    // ---- pre-projection ----
    for (int e = tid; e < CC*EXT; e += NTH) {
        int c = e / EXT;
        int j = e - c * EXT;
        sh[c*PADH + j] = sx0[j] * w_pre[c] + b_pre[c];
    }
    __syncthreads();

    const int cA = lane, cB = lane + 64, cD = lane + 128;
    const int g  = lane >> 4;
    const int c15 = lane & 15;

    #pragma unroll
    for (int li = 0; li < 3; ++li) {
        constexpr int DILA[3] = {1, 3, 9};
        constexpr int JLOA[3] = {1, 4, 13};
        const int dil = DILA[li];
        const int jlo = JLOA[li], jhi = EXT - JLOA[li];

        // ---- param staging for pointwise ----
        for (int i = tid; i < CC; i += NTH) {
            spb[i] = pw_b[li*CC + i];
            sg2[i] = n2_g[li*CC + i];
            sb2[i] = n2_b[li*CC + i];
        }

        // ---- depthwise dilated conv + LN1 + GELU -> syt (bf16, transposed) ----
        {
            float k0a = sep_w[(li*3+0)*CC + cA], k1a = sep_w[(li*3+1)*CC + cA], k2a = sep_w[(li*3+2)*CC + cA];
            float k0b = sep_w[(li*3+0)*CC + cB], k1b = sep_w[(li*3+1)*CC + cB], k2b = sep_w[(li*3+2)*CC + cB];
            float k0d = sep_w[(li*3+0)*CC + cD], k1d = sep_w[(li*3+1)*CC + cD], k2d = sep_w[(li*3+2)*CC + cD];
            float cba = sep_b[li*CC + cA], cbb = sep_b[li*CC + cB], cbd = sep_b[li*CC + cD];
            float g1a = n1_g[li*CC + cA], g1b = n1_g[li*CC + cB], g1d = n1_g[li*CC + cD];
            float b1a = n1_b[li*CC + cA], b1b = n1_b[li*CC + cB], b1d = n1_b[li*CC + cD];
            for (int j = jlo + wav; j < jhi; j += NW) {
                float m0 = smk[j-dil], m1 = smk[j], m2 = smk[j+dil];
                float aa = k0a*sh[cA*PADH + j-dil]*m0 + k1a*sh[cA*PADH + j]*m1 + k2a*sh[cA*PADH + j+dil]*m2 + cba;
                float ab = k0b*sh[cB*PADH + j-dil]*m0 + k1b*sh[cB*PADH + j]*m1 + k2b*sh[cB*PADH + j+dil]*m2 + cbb;
                float ad = k0d*sh[cD*PADH + j-dil]*m0 + k1d*sh[cD*PADH + j]*m1 + k2d*sh[cD*PADH + j+dil]*m2 + cbd;
                float s = aa+ab+ad, ss = aa*aa+ab*ab+ad*ad;
                #pragma unroll
                for (int mm = 1; mm < 64; mm <<= 1) { s += __shfl_xor(s, mm, 64); ss += __shfl_xor(ss, mm, 64); }
                float mean = s * (1.0f/CC);
                float var  = ss * (1.0f/CC) - mean*mean;
                float rstd = rsqrtf(var + 1e-5f);
                syt[j*LDK + cA] = (__bf16)gelu_exact((aa-mean)*rstd*g1a + b1a);
                syt[j*LDK + cB] = (__bf16)gelu_exact((ab-mean)*rstd*g1b + b1b);
                syt[j*LDK + cD] = (__bf16)gelu_exact((ad-mean)*rstd*g1d + b1d);
            }
        }
        __syncthreads();

        // ---- pointwise 192x192 via MFMA bf16: each wave owns one 16-col N-tile ----
        {
            const int nt = wav;                 // 0..4
            f32x4 acc[12];
            #pragma unroll
            for (int mt = 0; mt < 12; ++mt) {
                #pragma unroll
                for (int e = 0; e < 4; ++e) acc[mt][e] = spb[16*mt + 4*g + e];
            }
            const __bf16* wql = wq + (size_t)li * (6*12*512);
            #pragma unroll
            for (int ks = 0; ks < 6; ++ks) {
                bf16x8 bfrag = *(const bf16x8*)(syt + (16*nt + c15)*LDK + 32*ks + 8*g);
                const __bf16* ap = wql + (size_t)(ks*12)*512 + lane*8;
                #pragma unroll
                for (int mt = 0; mt < 12; ++mt) {
                    bf16x8 afrag = *(const bf16x8*)(ap + (size_t)mt*512);
                    acc[mt] = __builtin_amdgcn_mfma_f32_16x16x32_bf16(afrag, bfrag, acc[mt], 0, 0, 0);
                }
            }
            // ---- LN2 (in-register, cross-lane over 4 row-groups) + GELU + residual ----
            float s = 0.0f, ss = 0.0f;
            #pragma unroll
            for (int mt = 0; mt < 12; ++mt) {
                #pragma unroll
                for (int e = 0; e < 4; ++e) { float z = acc[mt][e]; s += z; ss += z*z; }
            }
            s  += __shfl_xor(s, 16, 64);  s  += __shfl_xor(s, 32, 64);
            ss += __shfl_xor(ss, 16, 64); ss += __shfl_xor(ss, 32, 64);
            float mean = s * (1.0f/CC);
            float var  = ss * (1.0f/CC) - mean*mean;
            float rstd = rsqrtf(var + 1e-5f);
            const int col = 16*nt + c15;
            if (col < EXT) {
                #pragma unroll
                for (int mt = 0; mt < 12; ++mt) {
                    #pragma unroll
                    for (int e = 0; e < 4; ++e) {
                        int ch = 16*mt + 4*g + e;
                        float v = gelu_exact((acc[mt][e]-mean)*rstd*sg2[ch] + sb2[ch]);
                        sh[ch*PADH + col] += v;
                    }
                }
            }
        }
        __syncthreads();
    }

    // ---- final projection: 29 spline params/col -> sproj (aliases syt) ----
    float* __restrict__ sproj = sytf;   // [63+..][33] fp32, stride 33 conflict-free
    for (int j = HALO + wav; j < HALO + INTR; j += NW) {
        if (lane < NPROJ) {
            const float* Wp = w_proj + lane*CC;
            float sum = 0.0f;
            for (int c4 = 0; c4 < CC; c4 += 4) {
                float4 wv = *(const float4*)(Wp + c4);
                sum += wv.x*sh[(c4+0)*PADH + j];
                sum += wv.y*sh[(c4+1)*PADH + j];
                sum += wv.z*sh[(c4+2)*PADH + j];
                sum += wv.w*sh[(c4+3)*PADH + j];
            }
            float mj = smk[j];
            sproj[j*33 + lane] = (sum*mj + b_proj[lane])*mj;
        }
    }
    __syncthreads();

    // ---- rational-quadratic spline + outputs (wave 0 only) ----
    if (tid < 64) {
        int j = HALO + tid;
        int t = t0 + j;
        float ladm = 0.0f;
        if (tid < INTR && t < TT) {
            const float SCALE = 0.07216878364870323f;  // 1/sqrt(192)
            float mj = smk[j];
            float uw[10], uh[10];
            #pragma unroll
            for (int k = 0; k < 10; ++k) {
                uw[k] = sproj[j*33 + k]      * SCALE;
                uh[k] = sproj[j*33 + 10 + k] * SCALE;
            }
            float mxw = uw[0];
            #pragma unroll
            for (int k = 1; k < 10; ++k) mxw = fmaxf(mxw, uw[k]);
            float ew[10]; float sew = 0.0f;
            #pragma unroll
            for (int k = 0; k < 10; ++k) { ew[k] = expf(uw[k]-mxw); sew += ew[k]; }
            float invw = 1.0f/sew;
            float cw[11]; cw[0] = -5.0f;
            float run = 0.0f;
            #pragma unroll
            for (int k = 0; k < 10; ++k) { run += 0.001f + 0.99f*ew[k]*invw; cw[k+1] = -5.0f + 10.0f*run; }
            cw[10] = 5.0f;
            float mxh = uh[0];
            #pragma unroll
            for (int k = 1; k < 10; ++k) mxh = fmaxf(mxh, uh[k]);
            float eh[10]; float seh = 0.0f;
            #pragma unroll
            for (int k = 0; k < 10; ++k) { eh[k] = expf(uh[k]-mxh); seh += eh[k]; }
            float invh = 1.0f/seh;
            float ch[11]; ch[0] = -5.0f;
            run = 0.0f;
            #pragma unroll
            for (int k = 0; k < 10; ++k) { run += 0.001f + 0.99f*eh[k]*invh; ch[k+1] = -5.0f + 10.0f*run; }
            ch[10] = 5.0f;
            float dd[11];
            dd[0] = 0.001f + softplus_s(0.5397424698f);
            #pragma unroll
            for (int k = 0; k < 9; ++k) dd[k+1] = 0.001f + softplus_s(sproj[j*33 + 20 + k]);
            dd[10] = dd[0];

            float xv = sx1[j];
            bool inside = (xv >= -5.0f) && (xv <= 5.0f);
            float xi = fminf(fmaxf(xv, -5.0f), 5.0f);
            int idx = 0;
            #pragma unroll
            for (int k = 1; k <= 9; ++k) idx = (xi >= cw[k]) ? k : idx;
            float in_cw=0, in_w=1, in_ch=0, in_h=1, in_d=1, d_p=1;
            #pragma unroll
            for (int k = 0; k < 10; ++k) {
                if (k == idx) {
                    in_cw = cw[k]; in_w = cw[k+1]-cw[k];
                    in_ch = ch[k]; in_h = ch[k+1]-ch[k];
                    in_d  = dd[k]; d_p  = dd[k+1];
                }
            }
            float delta = in_h/in_w;
            float th  = (xi - in_cw)/in_w;
            float th1 = th*(1.0f-th);
            float num = in_h*(delta*th*th + in_d*th1);
            float den = delta + (in_d + d_p - 2.0f*delta)*th1;
            float yv  = in_ch + num/den;
            float omt = 1.0f - th;
            float dnum = delta*delta*(d_p*th*th + 2.0f*delta*th1 + in_d*omt*omt);
            float lad = logf(dnum) - 2.0f*logf(den);
            if (!inside) { yv = xv; lad = 0.0f; }
            out[b*2*TT + t]      = sx0[j]*mj;
            out[b*2*TT + TT + t] = yv*mj;
            ladm = lad*mj;
        }
        #pragma unroll
        for (int mm = 1; mm < 64; mm <<= 1) ladm += __shfl_xor(ladm, mm, 64);
        if (tid == 0) atomicAdd(&logdet[b], ladm);
    }
}

extern "C" void kernel_launch(void* const* d_in, const int* in_sizes, int n_in,
                              void* d_out, int out_size, void* d_ws, size_t ws_size,
                              hipStream_t stream) {
    const float* x      = (const float*)d_in[0];
    const float* xmask  = (const float*)d_in[1];
    const float* w_pre  = (const float*)d_in[2];
    const float* b_pre  = (const float*)d_in[3];
    const float* sep_w  = (const float*)d_in[4];
    const float* sep_b  = (const float*)d_in[5];
    const float* pw_w   = (const float*)d_in[6];
    const float* pw_b   = (const float*)d_in[7];
    const float* n1_g   = (const float*)d_in[8];
    const float* n1_b   = (const float*)d_in[9];
    const float* n2_g   = (const float*)d_in[10];
    const float* n2_b   = (const float*)d_in[11];
    const float* w_proj = (const float*)d_in[12];
    const float* b_proj = (const float*)d_in[13];
    float* out = (float*)d_out;
    float* logdet = out + (size_t)BATCH*2*TT;
    __bf16* wq = (__bf16*)d_ws;         // 3*6*12*512 bf16 = 216 KiB

    hipMemsetAsync((void*)logdet, 0, BATCH*sizeof(float), stream);
    prepack_kernel<<<dim3((3*6*12*512 + 255)/256), 256, 0, stream>>>(pw_w, wq);

    size_t shbytes = (size_t)(CC*PADH + 8000 + 3*CC + 3*80) * sizeof(float);  // ~94.4 KiB
    dim3 grid(BATCH*NTILES);
    convflow_kernel<<<grid, NTH, shbytes, stream>>>(
        x, xmask, w_pre, b_pre, sep_w, sep_b, wq, pw_b,
        n1_g, n1_b, n2_g, n2_b, w_proj, b_proj, out, logdet);
}

// Round 3
// 306.839 us; speedup vs baseline: 10.0637x; 4.1176x over previous
//
#include <hip/hip_runtime.h>

#define CC    192
#define EXT   76
#define LDC   216         // bf16 elems per row (432 B); b128 frags ~2-way banks
#define NTH   512         // 8 waves
#define NW    8
#define HALO  13
#define INTR  50
#define TT    8192
#define BATCH 16
#define NTILES 164
#define NPROJ 29

#define WQ1_ELEMS (3*6*12*512)   // 110592
#define WQ2_ELEMS (6*2*512)      // 6144

typedef __bf16 bf16x8 __attribute__((ext_vector_type(8)));
typedef __bf16 bf16x4 __attribute__((ext_vector_type(4)));
typedef float  f32x4  __attribute__((ext_vector_type(4)));

// gelu via tanh-approx: gelu(v) = v * sigmoid(1.59577 v + 0.0713548 v^3)
__device__ __forceinline__ float gelu_fast(float v) {
    float vv = v * v;
    float u2 = v * fmaf(0.0713548162f, vv, 1.5957691216f);
    float t  = __expf(u2);                     // e^{2u}; inf-safe
    float r  = __builtin_amdgcn_rcpf(t + 1.0f);
    return v - v * r;                          // v * t/(t+1)
}
__device__ __forceinline__ float softplus_f(float v) {
    float e = __expf(-fabsf(v));
    return fmaxf(v, 0.0f) + __logf(1.0f + e);
}

// Prepack pw_w (3x192x192) + w_proj (29x192, padded to 32 rows) into MFMA
// A-fragment-ordered bf16.
__global__ __launch_bounds__(256) void prepack_kernel(
    const float* __restrict__ pw_w, const float* __restrict__ w_proj,
    __bf16* __restrict__ wq, __bf16* __restrict__ wq2) {
    int idx = blockIdx.x * 256 + threadIdx.x;
    if (idx < WQ1_ELEMS) {
        int e    = idx & 7;
        int lane = (idx >> 3) & 63;
        int r    = idx >> 9;
        int mt   = r % 12;
        int ks   = (r / 12) % 6;
        int li   = r / 72;
        int o = 16 * mt + (lane & 15);
        int c = 32 * ks + 8 * (lane >> 4) + e;
        wq[idx] = (__bf16)pw_w[((size_t)li * CC + o) * CC + c];
    } else if (idx < WQ1_ELEMS + WQ2_ELEMS) {
        int i2   = idx - WQ1_ELEMS;
        int e    = i2 & 7;
        int lane = (i2 >> 3) & 63;
        int r    = i2 >> 9;          // 0..11
        int mt   = r % 2;
        int ks   = r / 2;
        int row  = 16 * mt + (lane & 15);
        int c    = 32 * ks + 8 * (lane >> 4) + e;
        wq2[i2] = (row < NPROJ) ? (__bf16)w_proj[(size_t)row * CC + c] : (__bf16)0.0f;
    }
}

__global__ __launch_bounds__(NTH, 4) void convflow_kernel(
    const float* __restrict__ x, const float* __restrict__ xmask,
    const float* __restrict__ w_pre, const float* __restrict__ b_pre,
    const float* __restrict__ sep_w, const float* __restrict__ sep_b,
    const __bf16* __restrict__ wq, const __bf16* __restrict__ wq2,
    const float* __restrict__ pw_b,
    const float* __restrict__ n1_g, const float* __restrict__ n1_b,
    const float* __restrict__ n2_g, const float* __restrict__ n2_b,
    const float* __restrict__ b_proj,
    float* __restrict__ out, float* __restrict__ logdet)
{
    extern __shared__ char smemraw[];
    __bf16* __restrict__ sh_t = (__bf16*)smemraw;          // [80][216] residual h (transposed)
    __bf16* __restrict__ syt  = sh_t + 80 * LDC;           // [80][216] LN1/gelu out
    float*  __restrict__ sproj = (float*)syt;              // alias: [80][33] spline params
    float*  __restrict__ fbase = (float*)(syt + 80 * LDC);
    float*  __restrict__ spb = fbase;                      // [192]
    float*  __restrict__ sg2 = fbase + 192;                // [192]
    float*  __restrict__ sb2 = fbase + 384;                // [192]
    float*  __restrict__ sx0 = fbase + 576;                // [80]
    float*  __restrict__ sx1 = fbase + 656;                // [80]
    float*  __restrict__ smk = fbase + 736;                // [80]

    const int tid  = threadIdx.x;
    const int lane = tid & 63;
    const int wav  = tid >> 6;          // 0..7
    const int b    = blockIdx.x / NTILES;
    const int tile = blockIdx.x - b * NTILES;
    const int t0   = tile * INTR - HALO;

    // ---- stage 0: inputs; zero syt fully + sh_t tail rows ----
    for (int j = tid; j < 80; j += NTH) {
        int t = t0 + j;
        bool ok = (j < EXT) && (t >= 0) && (t < TT);
        sx0[j] = ok ? x[b*2*TT + t]      : 0.0f;
        sx1[j] = ok ? x[b*2*TT + TT + t] : 0.0f;
        smk[j] = ok ? xmask[b*TT + t]    : 0.0f;
    }
    for (int e = tid; e < 80*LDC/2; e += NTH) ((float*)syt)[e] = 0.0f;
    for (int e = tid; e < 4*LDC/2;  e += NTH) ((float*)(sh_t + 76*LDC))[e] = 0.0f;
    __syncthreads();

    // ---- pre-projection (transposed, bf16) + x0 output copy ----
    for (int e = tid; e < CC*EXT; e += NTH) {
        int c = e % CC;
        int j = e / CC;
        sh_t[j*LDC + c] = (__bf16)(sx0[j] * w_pre[c] + b_pre[c]);
    }
    for (int q = tid; q < INTR; q += NTH) {
        int t = t0 + HALO + q;
        if (t < TT) out[b*2*TT + t] = sx0[HALO+q] * smk[HALO+q];
    }
    __syncthreads();

    const int cA = lane, cB = lane + 64, cD = lane + 128;
    const int g   = lane >> 4;
    const int c15 = lane & 15;

    #pragma unroll
    for (int li = 0; li < 3; ++li) {
        constexpr int DILA[3] = {1, 3, 9};
        constexpr int JLOA[3] = {1, 4, 13};
        const int dil = DILA[li];
        const int jlo = JLOA[li], jhi = EXT - JLOA[li];

        for (int i = tid; i < CC; i += NTH) {
            spb[i] = pw_b[li*CC + i];
            sg2[i] = n2_g[li*CC + i];
            sb2[i] = n2_b[li*CC + i];
        }

        // ---- depthwise dilated conv + LN1 + gelu -> syt ----
        {
            float k0a = sep_w[(li*3+0)*CC + cA], k1a = sep_w[(li*3+1)*CC + cA], k2a = sep_w[(li*3+2)*CC + cA];
            float k0b = sep_w[(li*3+0)*CC + cB], k1b = sep_w[(li*3+1)*CC + cB], k2b = sep_w[(li*3+2)*CC + cB];
            float k0d = sep_w[(li*3+0)*CC + cD], k1d = sep_w[(li*3+1)*CC + cD], k2d = sep_w[(li*3+2)*CC + cD];
            float cba = sep_b[li*CC + cA], cbb = sep_b[li*CC + cB], cbd = sep_b[li*CC + cD];
            float g1a = n1_g[li*CC + cA], g1b = n1_g[li*CC + cB], g1d = n1_g[li*CC + cD];
            float b1a = n1_b[li*CC + cA], b1b = n1_b[li*CC + cB], b1d = n1_b[li*CC + cD];
            for (int j = jlo + wav; j < jhi; j += NW) {
                float m0 = smk[j-dil], m1 = smk[j], m2 = smk[j+dil];
                const __bf16* r0 = sh_t + (j-dil)*LDC;
                const __bf16* r1 = sh_t + j*LDC;
                const __bf16* r2 = sh_t + (j+dil)*LDC;
                float aa = k0a*(float)r0[cA]*m0 + k1a*(float)r1[cA]*m1 + k2a*(float)r2[cA]*m2 + cba;
                float ab = k0b*(float)r0[cB]*m0 + k1b*(float)r1[cB]*m1 + k2b*(float)r2[cB]*m2 + cbb;
                float ad = k0d*(float)r0[cD]*m0 + k1d*(float)r1[cD]*m1 + k2d*(float)r2[cD]*m2 + cbd;
                float s = aa+ab+ad, ss = aa*aa+ab*ab+ad*ad;
                #pragma unroll
                for (int mm = 1; mm < 64; mm <<= 1) { s += __shfl_xor(s, mm, 64); ss += __shfl_xor(ss, mm, 64); }
                float mean = s * (1.0f/CC);
                float var  = ss * (1.0f/CC) - mean*mean;
                float rstd = rsqrtf(var + 1e-5f);
                syt[j*LDC + cA] = (__bf16)gelu_fast((aa-mean)*rstd*g1a + b1a);
                syt[j*LDC + cB] = (__bf16)gelu_fast((ab-mean)*rstd*g1b + b1b);
                syt[j*LDC + cD] = (__bf16)gelu_fast((ad-mean)*rstd*g1d + b1d);
            }
        }
        __syncthreads();

        // ---- pointwise 192x192 MFMA (waves 0..4 each own a 16-col N-tile) ----
        if (wav < 5) {
            const int nt = wav;
            f32x4 acc[12];
            #pragma unroll
            for (int mt = 0; mt < 12; ++mt) {
                float4 pb = *(const float4*)(spb + 16*mt + 4*g);
                acc[mt][0] = pb.x; acc[mt][1] = pb.y; acc[mt][2] = pb.z; acc[mt][3] = pb.w;
            }
            const __bf16* wql = wq + (size_t)li * (6*12*512);
            #pragma unroll
            for (int ks = 0; ks < 6; ++ks) {
                bf16x8 bfrag = *(const bf16x8*)(syt + (16*nt + c15)*LDC + 32*ks + 8*g);
                const __bf16* ap = wql + (size_t)(ks*12)*512 + lane*8;
                #pragma unroll
                for (int mt = 0; mt < 12; ++mt) {
                    bf16x8 afrag = *(const bf16x8*)(ap + (size_t)mt*512);
                    acc[mt] = __builtin_amdgcn_mfma_f32_16x16x32_bf16(afrag, bfrag, acc[mt], 0, 0, 0);
                }
            }
            // LN2 in-register (xor 16/32 keeps c15 -> per-column reduce) + gelu + residual
            float s = 0.0f, ss = 0.0f;
            #pragma unroll
            for (int mt = 0; mt < 12; ++mt) {
                #pragma unroll
                for (int e = 0; e < 4; ++e) { float z = acc[mt][e]; s += z; ss += z*z; }
            }
            s  += __shfl_xor(s, 16, 64);  s  += __shfl_xor(s, 32, 64);
            ss += __shfl_xor(ss, 16, 64); ss += __shfl_xor(ss, 32, 64);
            float mean = s * (1.0f/CC);
            float var  = ss * (1.0f/CC) - mean*mean;
            float rstd = rsqrtf(var + 1e-5f);
            const int col = 16*nt + c15;
            if (col < EXT) {
                #pragma unroll
                for (int mt = 0; mt < 12; ++mt) {
                    float4 gv = *(const float4*)(sg2 + 16*mt + 4*g);
                    float4 bv = *(const float4*)(sb2 + 16*mt + 4*g);
                    bf16x4 hv = *(bf16x4*)(sh_t + (size_t)col*LDC + 16*mt + 4*g);
                    float v0 = gelu_fast((acc[mt][0]-mean)*rstd*gv.x + bv.x);
                    float v1 = gelu_fast((acc[mt][1]-mean)*rstd*gv.y + bv.y);
                    float v2 = gelu_fast((acc[mt][2]-mean)*rstd*gv.z + bv.z);
                    float v3 = gelu_fast((acc[mt][3]-mean)*rstd*gv.w + bv.w);
                    hv[0] = (__bf16)((float)hv[0] + v0);
                    hv[1] = (__bf16)((float)hv[1] + v1);
                    hv[2] = (__bf16)((float)hv[2] + v2);
                    hv[3] = (__bf16)((float)hv[3] + v3);
                    *(bf16x4*)(sh_t + (size_t)col*LDC + 16*mt + 4*g) = hv;
                }
            }
        }
        __syncthreads();
    }

    // ---- final projection via MFMA (waves 0..4) -> sproj[col][p] ----
    if (wav < 5) {
        const int nt = wav;
        f32x4 p0 = {0,0,0,0}, p1 = {0,0,0,0};
        #pragma unroll
        for (int ks = 0; ks < 6; ++ks) {
            bf16x8 bfrag = *(const bf16x8*)(sh_t + (16*nt + c15)*LDC + 32*ks + 8*g);
            bf16x8 a0 = *(const bf16x8*)(wq2 + (size_t)(ks*2+0)*512 + lane*8);
            bf16x8 a1 = *(const bf16x8*)(wq2 + (size_t)(ks*2+1)*512 + lane*8);
            p0 = __builtin_amdgcn_mfma_f32_16x16x32_bf16(a0, bfrag, p0, 0, 0, 0);
            p1 = __builtin_amdgcn_mfma_f32_16x16x32_bf16(a1, bfrag, p1, 0, 0, 0);
        }
        const int col = 16*nt + c15;
        if (col >= HALO && col < HALO + INTR) {
            float mj = smk[col];
            #pragma unroll
            for (int e = 0; e < 4; ++e) {
                int p = 4*g + e;
                sproj[col*33 + p] = (p0[e]*mj + b_proj[p])*mj;
            }
            #pragma unroll
            for (int e = 0; e < 4; ++e) {
                int p = 16 + 4*g + e;
                if (p < NPROJ) sproj[col*33 + p] = (p1[e]*mj + b_proj[p])*mj;
            }
        }
    }
    __syncthreads();

    // ---- rational-quadratic spline (wave 0) ----
    if (tid < 64) {
        int j = HALO + tid;
        int t = t0 + j;
        float ladm = 0.0f;
        if (tid < INTR && t < TT) {
            const float SCALE = 0.07216878364870323f;  // 1/sqrt(192)
            float mj = smk[j];
            float uw[10], uh[10];
            #pragma unroll
            for (int k = 0; k < 10; ++k) {
                uw[k] = sproj[j*33 + k]      * SCALE;
                uh[k] = sproj[j*33 + 10 + k] * SCALE;
            }
            float mxw = uw[0];
            #pragma unroll
            for (int k = 1; k < 10; ++k) mxw = fmaxf(mxw, uw[k]);
            float ew[10]; float sew = 0.0f;
            #pragma unroll
            for (int k = 0; k < 10; ++k) { ew[k] = __expf(uw[k]-mxw); sew += ew[k]; }
            float invw = 1.0f/sew;
            float cw[11]; cw[0] = -5.0f;
            float run = 0.0f;
            #pragma unroll
            for (int k = 0; k < 10; ++k) { run += 0.001f + 0.99f*ew[k]*invw; cw[k+1] = -5.0f + 10.0f*run; }
            cw[10] = 5.0f;
            float mxh = uh[0];
            #pragma unroll
            for (int k = 1; k < 10; ++k) mxh = fmaxf(mxh, uh[k]);
            float eh[10]; float seh = 0.0f;
            #pragma unroll
            for (int k = 0; k < 10; ++k) { eh[k] = __expf(uh[k]-mxh); seh += eh[k]; }
            float invh = 1.0f/seh;
            float ch[11]; ch[0] = -5.0f;
            run = 0.0f;
            #pragma unroll
            for (int k = 0; k < 10; ++k) { run += 0.001f + 0.99f*eh[k]*invh; ch[k+1] = -5.0f + 10.0f*run; }
            ch[10] = 5.0f;
            float dd[11];
            dd[0] = 1.0f;           // md + softplus(log(exp(1-md)-1)) == 1.0
            #pragma unroll
            for (int k = 0; k < 9; ++k) dd[k+1] = 0.001f + softplus_f(sproj[j*33 + 20 + k]);
            dd[10] = 1.0f;

            float xv = sx1[j];
            bool inside = (xv >= -5.0f) && (xv <= 5.0f);
            float xi = fminf(fmaxf(xv, -5.0f), 5.0f);
            int idx = 0;
            #pragma unroll
            for (int k = 1; k <= 9; ++k) idx = (xi >= cw[k]) ? k : idx;
            float in_cw=0, in_w=1, in_ch=0, in_h=1, in_d=1, d_p=1;
            #pragma unroll
            for (int k = 0; k < 10; ++k) {
                if (k == idx) {
                    in_cw = cw[k]; in_w = cw[k+1]-cw[k];
                    in_ch = ch[k]; in_h = ch[k+1]-ch[k];
                    in_d  = dd[k]; d_p  = dd[k+1];
                }
            }
            float delta = in_h/in_w;
            float th  = (xi - in_cw)/in_w;
            float th1 = th*(1.0f-th);
            float num = in_h*(delta*th*th + in_d*th1);
            float den = delta + (in_d + d_p - 2.0f*delta)*th1;
            float yv  = in_ch + num/den;
            float omt = 1.0f - th;
            float dnum = delta*delta*(d_p*th*th + 2.0f*delta*th1 + in_d*omt*omt);
            float lad = __logf(dnum) - 2.0f*__logf(den);
            if (!inside) { yv = xv; lad = 0.0f; }
            out[b*2*TT + TT + t] = yv*mj;
            ladm = lad*mj;
        }
        #pragma unroll
        for (int mm = 1; mm < 64; mm <<= 1) ladm += __shfl_xor(ladm, mm, 64);
        if (tid == 0) atomicAdd(&logdet[b], ladm);
    }
}

extern "C" void kernel_launch(void* const* d_in, const int* in_sizes, int n_in,
                              void* d_out, int out_size, void* d_ws, size_t ws_size,
                              hipStream_t stream) {
    const float* x      = (const float*)d_in[0];
    const float* xmask  = (const float*)d_in[1];
    const float* w_pre  = (const float*)d_in[2];
    const float* b_pre  = (const float*)d_in[3];
    const float* sep_w  = (const float*)d_in[4];
    const float* sep_b  = (const float*)d_in[5];
    const float* pw_w   = (const float*)d_in[6];
    const float* pw_b   = (const float*)d_in[7];
    const float* n1_g   = (const float*)d_in[8];
    const float* n1_b   = (const float*)d_in[9];
    const float* n2_g   = (const float*)d_in[10];
    const float* n2_b   = (const float*)d_in[11];
    const float* w_proj = (const float*)d_in[12];
    const float* b_proj = (const float*)d_in[13];
    float* out = (float*)d_out;
    float* logdet = out + (size_t)BATCH*2*TT;
    __bf16* wq  = (__bf16*)d_ws;
    __bf16* wq2 = wq + WQ1_ELEMS;

    hipMemsetAsync((void*)logdet, 0, BATCH*sizeof(float), stream);
    prepack_kernel<<<dim3((WQ1_ELEMS + WQ2_ELEMS + 255)/256), 256, 0, stream>>>(
        pw_w, w_proj, wq, wq2);

    size_t shbytes = (size_t)(2 * 80 * LDC * 2 + 816 * 4);   // 72384 B -> 2 blocks/CU
    dim3 grid(BATCH*NTILES);
    convflow_kernel<<<grid, NTH, shbytes, stream>>>(
        x, xmask, w_pre, b_pre, sep_w, sep_b, wq, wq2, pw_b,
        n1_g, n1_b, n2_g, n2_b, b_proj, out, logdet);
}

// Round 4
// 255.426 us; speedup vs baseline: 12.0894x; 1.2013x over previous
//
#include <hip/hip_runtime.h>

#define CC    192
#define EXT   64
#define LDC   216         // bf16 row stride (432 B): b128 frags 2-way banks (free)
#define NTH   512         // 8 waves
#define NW    8
#define HALO  13
#define INTR  38
#define TT    8192
#define BATCH 16
#define NTILES 216        // ceil(8192/38)
#define NPROJ 29

#define WQ1_ELEMS (3*6*12*512)   // 110592
#define WQ2_ELEMS (6*2*512)      // 6144

typedef __bf16 bf16x8 __attribute__((ext_vector_type(8)));
typedef __bf16 bf16x4 __attribute__((ext_vector_type(4)));
typedef float  f32x4  __attribute__((ext_vector_type(4)));

// gelu via tanh-approx: gelu(v) = v * sigmoid(1.59577 v + 0.0713548 v^3)
__device__ __forceinline__ float gelu_fast(float v) {
    float vv = v * v;
    float u2 = v * fmaf(0.0713548162f, vv, 1.5957691216f);
    float t  = __expf(u2);
    float r  = __builtin_amdgcn_rcpf(t + 1.0f);
    return v - v * r;
}
__device__ __forceinline__ float softplus_f(float v) {
    float e = __expf(-fabsf(v));
    return fmaxf(v, 0.0f) + __logf(1.0f + e);
}

// Prepack pw_w (3x192x192) + w_proj (29x192 -> 32 rows) into MFMA A-frag bf16.
__global__ __launch_bounds__(256) void prepack_kernel(
    const float* __restrict__ pw_w, const float* __restrict__ w_proj,
    __bf16* __restrict__ wq, __bf16* __restrict__ wq2) {
    int idx = blockIdx.x * 256 + threadIdx.x;
    if (idx < WQ1_ELEMS) {
        int e    = idx & 7;
        int lane = (idx >> 3) & 63;
        int r    = idx >> 9;
        int mt   = r % 12;
        int ks   = (r / 12) % 6;
        int li   = r / 72;
        int o = 16 * mt + (lane & 15);
        int c = 32 * ks + 8 * (lane >> 4) + e;
        wq[idx] = (__bf16)pw_w[((size_t)li * CC + o) * CC + c];
    } else if (idx < WQ1_ELEMS + WQ2_ELEMS) {
        int i2   = idx - WQ1_ELEMS;
        int e    = i2 & 7;
        int lane = (i2 >> 3) & 63;
        int r    = i2 >> 9;          // 0..11  = ks*2 + pr
        int pr   = r % 2;
        int ks   = r / 2;
        int row  = 16 * pr + (lane & 15);
        int c    = 32 * ks + 8 * (lane >> 4) + e;
        wq2[i2] = (row < NPROJ) ? (__bf16)w_proj[(size_t)row * CC + c] : (__bf16)0.0f;
    }
}

__global__ __launch_bounds__(NTH, 4) void convflow_kernel(
    const float* __restrict__ x, const float* __restrict__ xmask,
    const float* __restrict__ w_pre, const float* __restrict__ b_pre,
    const float* __restrict__ sep_w, const float* __restrict__ sep_b,
    const __bf16* __restrict__ wq, const __bf16* __restrict__ wq2,
    const float* __restrict__ pw_b,
    const float* __restrict__ n1_g, const float* __restrict__ n1_b,
    const float* __restrict__ n2_g, const float* __restrict__ n2_b,
    const float* __restrict__ b_proj,
    float* __restrict__ out, float* __restrict__ logdet)
{
    extern __shared__ char smemraw[];
    __bf16* __restrict__ sh_t = (__bf16*)smemraw;          // [64][216] residual h
    __bf16* __restrict__ syt  = sh_t + EXT * LDC;          // [64][216] LN1/gelu out
    float*  __restrict__ sproj = (float*)syt;              // alias: [64][33]
    float*  __restrict__ fbase = (float*)(syt + EXT * LDC);
    float*  __restrict__ spb = fbase;                      // [192]
    float*  __restrict__ sg2 = fbase + 192;
    float*  __restrict__ sb2 = fbase + 384;
    float*  __restrict__ sx0 = fbase + 576;                // [64]
    float*  __restrict__ sx1 = fbase + 640;
    float*  __restrict__ smk = fbase + 704;
    float2* __restrict__ sred = (float2*)(fbase + 768);    // [64][2]

    const int tid  = threadIdx.x;
    const int lane = tid & 63;
    const int wav  = tid >> 6;          // 0..7
    const int b    = blockIdx.x / NTILES;
    const int tile = blockIdx.x - b * NTILES;
    const int t0   = tile * INTR - HALO;

    // ---- stage 0: inputs ----
    for (int j = tid; j < EXT; j += NTH) {
        int t = t0 + j;
        bool ok = (t >= 0) && (t < TT);
        sx0[j] = ok ? x[b*2*TT + t]      : 0.0f;
        sx1[j] = ok ? x[b*2*TT + TT + t] : 0.0f;
        smk[j] = ok ? xmask[b*TT + t]    : 0.0f;
    }
    __syncthreads();

    // ---- pre-projection (transposed bf16) + x0 output copy ----
    for (int e = tid; e < CC*EXT; e += NTH) {
        int c = e % CC;
        int j = e / CC;
        sh_t[j*LDC + c] = (__bf16)(sx0[j] * w_pre[c] + b_pre[c]);
    }
    for (int q = tid; q < INTR; q += NTH) {
        int t = t0 + HALO + q;
        if (t < TT) out[b*2*TT + t] = sx0[HALO+q] * smk[HALO+q];
    }
    __syncthreads();

    const int g   = lane >> 4;
    const int c15 = lane & 15;
    const int cl  = lane & 31;          // conv channel base
    const int sub = lane >> 5;          // conv column selector (0/1)
    const int nt   = wav & 3;           // pointwise N-tile
    const int half = wav >> 2;          // pointwise M-half

    #pragma unroll
    for (int li = 0; li < 3; ++li) {
        constexpr int DILA[3] = {1, 3, 9};
        constexpr int JLOA[3] = {1, 4, 13};
        constexpr int JHIA[3] = {63, 60, 51};
        const int dil = DILA[li];
        const int jlo = JLOA[li], jhi = JHIA[li];

        for (int i = tid; i < CC; i += NTH) {
            spb[i] = pw_b[li*CC + i];
            sg2[i] = n2_g[li*CC + i];
            sb2[i] = n2_b[li*CC + i];
        }

        // ---- depthwise conv + LN1 + gelu -> syt (32 lanes x 2 cols, 6 ch/lane) ----
        {
            float k0[6], k1[6], k2[6], cb[6], g1[6], b1[6];
            #pragma unroll
            for (int k = 0; k < 6; ++k) {
                int c = cl + 32*k;
                k0[k] = sep_w[(li*3+0)*CC + c];
                k1[k] = sep_w[(li*3+1)*CC + c];
                k2[k] = sep_w[(li*3+2)*CC + c];
                cb[k] = sep_b[li*CC + c];
                g1[k] = n1_g[li*CC + c];
                b1[k] = n1_b[li*CC + c];
            }
            for (int j = jlo + 2*wav + sub; j < jhi; j += 16) {
                float m0 = smk[j-dil], m1 = smk[j], m2 = smk[j+dil];
                const __bf16* r0 = sh_t + (j-dil)*LDC;
                const __bf16* r1 = sh_t + j*LDC;
                const __bf16* r2 = sh_t + (j+dil)*LDC;
                float a[6]; float s = 0.0f, ss = 0.0f;
                #pragma unroll
                for (int k = 0; k < 6; ++k) {
                    int c = cl + 32*k;
                    float v = k0[k]*(float)r0[c]*m0 + k1[k]*(float)r1[c]*m1
                            + k2[k]*(float)r2[c]*m2 + cb[k];
                    a[k] = v; s += v; ss += v*v;
                }
                #pragma unroll
                for (int mm = 1; mm < 32; mm <<= 1) {
                    s  += __shfl_xor(s,  mm, 64);
                    ss += __shfl_xor(ss, mm, 64);
                }
                float mean = s * (1.0f/CC);
                float var  = ss * (1.0f/CC) - mean*mean;
                float rstd = rsqrtf(var + 1e-5f);
                #pragma unroll
                for (int k = 0; k < 6; ++k)
                    syt[j*LDC + cl + 32*k] = (__bf16)gelu_fast((a[k]-mean)*rstd*g1[k] + b1[k]);
            }
        }
        __syncthreads();

        // ---- pointwise 192x192 MFMA: 8 jobs = (nt 0..3) x (M-half 0..1) ----
        {
            f32x4 acc[6];
            #pragma unroll
            for (int q = 0; q < 6; ++q) {
                float4 pb = *(const float4*)(spb + 16*(6*half+q) + 4*g);
                acc[q][0] = pb.x; acc[q][1] = pb.y; acc[q][2] = pb.z; acc[q][3] = pb.w;
            }
            const __bf16* wql = wq + (size_t)li * (6*12*512);
            #pragma unroll
            for (int ks = 0; ks < 6; ++ks) {
                bf16x8 bfrag = *(const bf16x8*)(syt + (16*nt + c15)*LDC + 32*ks + 8*g);
                const __bf16* ap = wql + (size_t)(ks*12 + 6*half)*512 + lane*8;
                #pragma unroll
                for (int q = 0; q < 6; ++q) {
                    bf16x8 afrag = *(const bf16x8*)(ap + (size_t)q*512);
                    acc[q] = __builtin_amdgcn_mfma_f32_16x16x32_bf16(afrag, bfrag, acc[q], 0, 0, 0);
                }
            }
            // partial LN2 stats over this half's 96 channels
            float s = 0.0f, ss = 0.0f;
            #pragma unroll
            for (int q = 0; q < 6; ++q) {
                #pragma unroll
                for (int e = 0; e < 4; ++e) { float z = acc[q][e]; s += z; ss += z*z; }
            }
            s  += __shfl_xor(s, 16, 64);  s  += __shfl_xor(s, 32, 64);
            ss += __shfl_xor(ss, 16, 64); ss += __shfl_xor(ss, 32, 64);
            if (lane < 16) sred[(16*nt + lane)*2 + half] = make_float2(s, ss);
            __syncthreads();
            const int col = 16*nt + c15;
            float2 e0 = sred[col*2], e1 = sred[col*2+1];
            float mean = (e0.x + e1.x) * (1.0f/CC);
            float var  = (e0.y + e1.y) * (1.0f/CC) - mean*mean;
            float rstd = rsqrtf(var + 1e-5f);
            #pragma unroll
            for (int q = 0; q < 6; ++q) {
                int mt = 6*half + q;
                float4 gv = *(const float4*)(sg2 + 16*mt + 4*g);
                float4 bv = *(const float4*)(sb2 + 16*mt + 4*g);
                bf16x4 hv = *(bf16x4*)(sh_t + (size_t)col*LDC + 16*mt + 4*g);
                hv[0] = (__bf16)((float)hv[0] + gelu_fast((acc[q][0]-mean)*rstd*gv.x + bv.x));
                hv[1] = (__bf16)((float)hv[1] + gelu_fast((acc[q][1]-mean)*rstd*gv.y + bv.y));
                hv[2] = (__bf16)((float)hv[2] + gelu_fast((acc[q][2]-mean)*rstd*gv.z + bv.z));
                hv[3] = (__bf16)((float)hv[3] + gelu_fast((acc[q][3]-mean)*rstd*gv.w + bv.w));
                *(bf16x4*)(sh_t + (size_t)col*LDC + 16*mt + 4*g) = hv;
            }
        }
        __syncthreads();
    }

    // ---- final projection: 8 jobs = (nt 0..3) x (row-half 0..1) ----
    {
        const int pr = half;
        f32x4 p0 = {0,0,0,0};
        #pragma unroll
        for (int ks = 0; ks < 6; ++ks) {
            bf16x8 bfrag = *(const bf16x8*)(sh_t + (16*nt + c15)*LDC + 32*ks + 8*g);
            bf16x8 a0 = *(const bf16x8*)(wq2 + (size_t)(ks*2 + pr)*512 + lane*8);
            p0 = __builtin_amdgcn_mfma_f32_16x16x32_bf16(a0, bfrag, p0, 0, 0, 0);
        }
        const int col = 16*nt + c15;
        if (col >= HALO && col < HALO + INTR) {
            float mj = smk[col];
            #pragma unroll
            for (int e = 0; e < 4; ++e) {
                int p = 16*pr + 4*g + e;
                if (p < NPROJ) sproj[col*33 + p] = (p0[e]*mj + b_proj[p])*mj;
            }
        }
    }
    __syncthreads();

    // ---- rational-quadratic spline (wave 0) ----
    if (tid < 64) {
        int j = HALO + tid;
        int t = t0 + j;
        float ladm = 0.0f;
        if (tid < INTR && t < TT) {
            const float SCALE = 0.07216878364870323f;  // 1/sqrt(192)
            float mj = smk[j];
            float uw[10], uh[10];
            #pragma unroll
            for (int k = 0; k < 10; ++k) {
                uw[k] = sproj[j*33 + k]      * SCALE;
                uh[k] = sproj[j*33 + 10 + k] * SCALE;
            }
            float mxw = uw[0];
            #pragma unroll
            for (int k = 1; k < 10; ++k) mxw = fmaxf(mxw, uw[k]);
            float ew[10]; float sew = 0.0f;
            #pragma unroll
            for (int k = 0; k < 10; ++k) { ew[k] = __expf(uw[k]-mxw); sew += ew[k]; }
            float invw = 1.0f/sew;
            float cw[11]; cw[0] = -5.0f;
            float run = 0.0f;
            #pragma unroll
            for (int k = 0; k < 10; ++k) { run += 0.001f + 0.99f*ew[k]*invw; cw[k+1] = -5.0f + 10.0f*run; }
            cw[10] = 5.0f;
            float mxh = uh[0];
            #pragma unroll
            for (int k = 1; k < 10; ++k) mxh = fmaxf(mxh, uh[k]);
            float eh[10]; float seh = 0.0f;
            #pragma unroll
            for (int k = 0; k < 10; ++k) { eh[k] = __expf(uh[k]-mxh); seh += eh[k]; }
            float invh = 1.0f/seh;
            float ch[11]; ch[0] = -5.0f;
            run = 0.0f;
            #pragma unroll
            for (int k = 0; k < 10; ++k) { run += 0.001f + 0.99f*eh[k]*invh; ch[k+1] = -5.0f + 10.0f*run; }
            ch[10] = 5.0f;
            float dd[11];
            dd[0] = 1.0f;
            #pragma unroll
            for (int k = 0; k < 9; ++k) dd[k+1] = 0.001f + softplus_f(sproj[j*33 + 20 + k]);
            dd[10] = 1.0f;

            float xv = sx1[j];
            bool inside = (xv >= -5.0f) && (xv <= 5.0f);
            float xi = fminf(fmaxf(xv, -5.0f), 5.0f);
            int idx = 0;
            #pragma unroll
            for (int k = 1; k <= 9; ++k) idx = (xi >= cw[k]) ? k : idx;
            float in_cw=0, in_w=1, in_ch=0, in_h=1, in_d=1, d_p=1;
            #pragma unroll
            for (int k = 0; k < 10; ++k) {
                if (k == idx) {
                    in_cw = cw[k]; in_w = cw[k+1]-cw[k];
                    in_ch = ch[k]; in_h = ch[k+1]-ch[k];
                    in_d  = dd[k]; d_p  = dd[k+1];
                }
            }
            float delta = in_h/in_w;
            float th  = (xi - in_cw)/in_w;
            float th1 = th*(1.0f-th);
            float num = in_h*(delta*th*th + in_d*th1);
            float den = delta + (in_d + d_p - 2.0f*delta)*th1;
            float yv  = in_ch + num/den;
            float omt = 1.0f - th;
            float dnum = delta*delta*(d_p*th*th + 2.0f*delta*th1 + in_d*omt*omt);
            float lad = __logf(dnum) - 2.0f*__logf(den);
            if (!inside) { yv = xv; lad = 0.0f; }
            out[b*2*TT + TT + t] = yv*mj;
            ladm = lad*mj;
        }
        #pragma unroll
        for (int mm = 1; mm < 64; mm <<= 1) ladm += __shfl_xor(ladm, mm, 64);
        if (tid == 0) atomicAdd(&logdet[b], ladm);
    }
}

extern "C" void kernel_launch(void* const* d_in, const int* in_sizes, int n_in,
                              void* d_out, int out_size, void* d_ws, size_t ws_size,
                              hipStream_t stream) {
    const float* x      = (const float*)d_in[0];
    const float* xmask  = (const float*)d_in[1];
    const float* w_pre  = (const float*)d_in[2];
    const float* b_pre  = (const float*)d_in[3];
    const float* sep_w  = (const float*)d_in[4];
    const float* sep_b  = (const float*)d_in[5];
    const float* pw_w   = (const float*)d_in[6];
    const float* pw_b   = (const float*)d_in[7];
    const float* n1_g   = (const float*)d_in[8];
    const float* n1_b   = (const float*)d_in[9];
    const float* n2_g   = (const float*)d_in[10];
    const float* n2_b   = (const float*)d_in[11];
    const float* w_proj = (const float*)d_in[12];
    const float* b_proj = (const float*)d_in[13];
    float* out = (float*)d_out;
    float* logdet = out + (size_t)BATCH*2*TT;
    __bf16* wq  = (__bf16*)d_ws;
    __bf16* wq2 = wq + WQ1_ELEMS;

    hipMemsetAsync((void*)logdet, 0, BATCH*sizeof(float), stream);
    prepack_kernel<<<dim3((WQ1_ELEMS + WQ2_ELEMS + 255)/256), 256, 0, stream>>>(
        pw_w, w_proj, wq, wq2);

    size_t shbytes = (size_t)(2*EXT*LDC*2 + 768*4 + 64*2*8);   // 59392 B -> 2 blocks/CU
    dim3 grid(BATCH*NTILES);
    convflow_kernel<<<grid, NTH, shbytes, stream>>>(
        x, xmask, w_pre, b_pre, sep_w, sep_b, wq, wq2, pw_b,
        n1_g, n1_b, n2_g, n2_b, b_proj, out, logdet);
}